// Round 4
// baseline (309.659 us; speedup 1.0000x reference)
//
#include <hip/hip_runtime.h>
#include <hip/hip_bf16.h>

// B=2048, N=64, C=256, F=256
// out[b,n,f] = d[f,n]*h0[b,n,f] + sum_m off[f,n,m]*h1[b,m,f] + bias[f]
// v4: k_pre (softmax prep + Wt + x->bf16) then fused k_main using
// global_load_lds staging (m97 structure), XOR-swizzled LDS, 48KB arena
// (3 blocks/CU), einsum on LDS-resident h1, single out write.

typedef __attribute__((ext_vector_type(8))) short  fragA;   // 8 bf16 = 4 VGPR
typedef __attribute__((ext_vector_type(4))) float  f32x4;
typedef __attribute__((ext_vector_type(8))) unsigned short u16x8;
typedef __attribute__((ext_vector_type(4))) unsigned short u16x4;

// workspace layout (bytes)
constexpr long OFF_OFF = 0;                          // bf16 off [256][64][64] (2 MB)
constexpr long OFF_WT  = 2l * 1024 * 1024;           // bf16 Wt flat [512][256] (256 KB)
constexpr long OFF_DS  = OFF_WT + 512l * 256 * 2;    // f32 dscale [64][256]   (64 KB)
constexpr long OFF_XB  = OFF_DS + 64l * 256 * 4;     // bf16 xb [131072][256]  (67 MB)
constexpr long WS_NEED = OFF_XB + 131072l * 256 * 2;

static __device__ inline unsigned short f2bf(float f) {
  __hip_bfloat16 h = __float2bfloat16(f);
  return __builtin_bit_cast(unsigned short, h);
}
static __device__ inline float bf2f(unsigned short u) {
  unsigned int x = ((unsigned int)u) << 16;
  return __builtin_bit_cast(float, x);
}
static __device__ __forceinline__ void gl16(const void* g, void* l) {
  __builtin_amdgcn_global_load_lds(
      (const __attribute__((address_space(1))) unsigned int*)g,
      (__attribute__((address_space(3))) unsigned int*)l, 16, 0, 0);
}
static __device__ __forceinline__ f32x4 mfma16(fragA a, fragA b, f32x4 c) {
  return __builtin_amdgcn_mfma_f32_16x16x32_bf16(a, b, c, 0, 0, 0);
}

// ---------------------------------------------------------------- k_pre
// blocks 0..4095: softmax prep; 4096..6143: x->bf16; 6144..6175: W->Wt
__global__ __launch_bounds__(256) void k_pre(const float* __restrict__ x,
                                             const float* __restrict__ e,
                                             const float* __restrict__ W,
                                             const unsigned char* __restrict__ mask,
                                             char* __restrict__ ws_b) {
  const int bid = blockIdx.x;
  const int tid = threadIdx.x;
  if (bid < 4096) {
    unsigned short* off = (unsigned short*)(ws_b + OFF_OFF);
    float* dscale = (float*)(ws_b + OFF_DS);
    const int lane = tid & 63;
    const int row  = bid * 4 + (tid >> 6);   // f*64 + n
    const int n = row & 63;
    bool is_u8 = __all(mask[lane * 65] != 0);  // diag guaranteed true
    bool mv;
    if (is_u8) mv = mask[n * 64 + lane] != 0;
    else       mv = ((const int*)mask)[n * 64 + lane] != 0;
    float v = mv ? e[(long)row * 64 + lane] : -1e30f;
    float mx = v;
#pragma unroll
    for (int s = 32; s; s >>= 1) mx = fmaxf(mx, __shfl_xor(mx, s));
    float ex = mv ? __expf(v - mx) : 0.f;
    float sm = ex;
#pragma unroll
    for (int s = 32; s; s >>= 1) sm += __shfl_xor(sm, s);
    float adj = ex / sm;
    const int f = row >> 6;
    if (lane == n) dscale[n * 256 + f] = adj;
    off[(long)row * 64 + lane] = f2bf(lane == n ? 0.f : adj);
  } else if (bid < 6144) {
    unsigned short* xb = (unsigned short*)(ws_b + OFF_XB);
    long i = ((long)(bid - 4096) * 256 + tid) * 8;
    const long stride = 2048l * 256 * 8;
    const long total = 131072l * 256;
    for (; i < total; i += stride) {
      float4 a = *(const float4*)(x + i);
      float4 b = *(const float4*)(x + i + 4);
      u16x8 p;
      p[0] = f2bf(a.x); p[1] = f2bf(a.y); p[2] = f2bf(a.z); p[3] = f2bf(a.w);
      p[4] = f2bf(b.x); p[5] = f2bf(b.y); p[6] = f2bf(b.z); p[7] = f2bf(b.w);
      *(u16x8*)(xb + i) = p;
    }
  } else {
    unsigned short* Wt = (unsigned short*)(ws_b + OFF_WT);
    __shared__ float t[64][65];
    const int b2 = bid - 6144;          // 32 blocks: w(2) x f0(4) x c0(4)
    const int w = b2 >> 4, f0 = ((b2 >> 2) & 3) * 64, c0 = (b2 & 3) * 64;
    const int tr = tid >> 2, tc = (tid & 3) * 16;
    const float* src = W + ((long)(w * 256 + c0 + tr)) * 256 + f0 + tc;
#pragma unroll
    for (int i = 0; i < 16; i += 4) {
      float4 v = *(const float4*)(src + i);
      t[tr][tc + i] = v.x; t[tr][tc + i + 1] = v.y;
      t[tr][tc + i + 2] = v.z; t[tr][tc + i + 3] = v.w;
    }
    __syncthreads();
    u16x8 p0, p1;
#pragma unroll
    for (int i = 0; i < 8; i++)  p0[i] = f2bf(t[tc + i][tr]);
#pragma unroll
    for (int i = 0; i < 8; i++)  p1[i] = f2bf(t[tc + 8 + i][tr]);
    unsigned short* dst = Wt + ((long)(w * 256 + f0 + tr)) * 256 + c0 + tc;
    *(u16x8*)dst = p0;
    *(u16x8*)(dst + 8) = p1;
  }
}

// ---------------------------------------------------------------- k_main
// grid 8192 (fb = wg&7 -> XCD-resident off slice; rg = wg>>3), block 256.
// Tile: 128 rows (2 batches) x 64 cols (32 f x {h0,h1}), K=256 in 4 steps.
// Arena: [0,16K) A-tile (later Hb), [16K,48K) B-tile. All XOR-swizzled.
__global__ __launch_bounds__(256) void k_main(const float* __restrict__ bias,
                                              const char* __restrict__ ws_b,
                                              float* __restrict__ out) {
  const unsigned short* offp = (const unsigned short*)(ws_b + OFF_OFF);
  const float* dscale        = (const float*)(ws_b + OFF_DS);
  const char* xb_b = ws_b + OFF_XB;
  const char* wt_b = ws_b + OFF_WT;

  __shared__ __align__(16) char arena[49152];
  unsigned short* Hb = (unsigned short*)arena;   // einsum phase: [f][b][m], stride 136

  const int tid = threadIdx.x;
  const int wid = tid >> 6, lane = tid & 63;
  const int lr = lane & 15, qu = lane >> 4;

  const int wg = blockIdx.x;
  const int f0 = (wg & 7) * 32;
  const long R0 = (long)(wg >> 3) * 128;

  // ---- stage B once: 64 cols x 512B, source pre-permuted for XOR swizzle
  {
    const int c  = tid >> 5;             // col within 8-group
    const int cb = (tid & 31) * 16;
    const int sw = cb ^ ((c & 7) << 4);
#pragma unroll
    for (int i = 0; i < 8; i++) {
      int col  = i * 8 + c;
      int wrow = (col < 32) ? (f0 + col) : (224 + f0 + col);  // 256+f0+(col-32)
      gl16(wt_b + (long)wrow * 512 + sw, arena + 16384 + i * 4096 + tid * 16);
    }
  }
  // ---- stage A (ks=0)
  const int ar = tid >> 3;                       // row within 32-group
  const int aswz = ((tid & 7) ^ (ar & 7)) << 4;  // permuted 16B slot in 128B chunk
#pragma unroll
  for (int i = 0; i < 4; i++)
    gl16(xb_b + (R0 + i * 32 + ar) * 512 + aswz, arena + i * 4096 + tid * 16);

  f32x4 acc[2][4] = {};
  const int arow0 = wid * 32;

  for (int ks = 0; ks < 4; ks++) {
    __syncthreads();                 // drains vmcnt(0): staged tiles visible
    fragA af[2][2], bf_[2][4];
#pragma unroll
    for (int kk = 0; kk < 2; kk++) {
#pragma unroll
      for (int i2 = 0; i2 < 2; i2++) {
        int r = arow0 + i2 * 16 + lr;
        af[kk][i2] = *(const fragA*)(arena + r * 128 +
                        ((kk * 64 + qu * 16) ^ ((lr & 7) << 4)));
      }
#pragma unroll
      for (int j = 0; j < 4; j++) {
        int cc = j * 16 + lr;
        bf_[kk][j] = *(const fragA*)(arena + 16384 + cc * 512 +
                        ((ks * 128 + kk * 64 + qu * 16) ^ ((lr & 7) << 4)));
      }
    }
#pragma unroll
    for (int kk = 0; kk < 2; kk++)
#pragma unroll
      for (int i2 = 0; i2 < 2; i2++)
#pragma unroll
        for (int j = 0; j < 4; j++)
          acc[i2][j] = mfma16(af[kk][i2], bf_[kk][j], acc[i2][j]);
    __syncthreads();                 // all waves done reading A-tile
    if (ks < 3) {
#pragma unroll
      for (int i = 0; i < 4; i++)
        gl16(xb_b + (R0 + i * 32 + ar) * 512 + (ks + 1) * 128 + aswz,
             arena + i * 4096 + tid * 16);
    }
  }

  // ---- h1 (cols 32..63) -> Hb[f][b][m] (A region is dead after last barrier)
  const int hb_b = wid >> 1;             // batch index of wave's rows
  const int hm0 = (wid & 1) * 32;
#pragma unroll
  for (int j = 2; j < 4; j++) {
#pragma unroll
    for (int i2 = 0; i2 < 2; i2++) {
      int f = (j - 2) * 16 + lr;
      int m = hm0 + i2 * 16 + qu * 4;
      u16x4 pk;
      pk[0] = f2bf(acc[i2][j][0]); pk[1] = f2bf(acc[i2][j][1]);
      pk[2] = f2bf(acc[i2][j][2]); pk[3] = f2bf(acc[i2][j][3]);
      *(u16x4*)(Hb + f * 136 + hb_b * 64 + m) = pk;
    }
  }
  __syncthreads();

  // ---- einsum: wave owns f = wid*8+q. C[n,b] = sum_m off[f,n,m]*h1[b,m].
  // A = off rows n (global, L2-resident slice); B = h1 cols b (2 of 16 valid).
  // Result bf16 written in place over Hb[f] (wave-private f).
#pragma unroll 2
  for (int q = 0; q < 8; q++) {
    int fl = wid * 8 + q;
    const unsigned short* ob = offp + (long)(f0 + fl) * 4096;
    f32x4 ea[4] = {};
#pragma unroll
    for (int kk = 0; kk < 2; kk++) {
      fragA hbf = *(const fragA*)(Hb + fl * 136 + (lr & 1) * 64 + kk * 32 + qu * 8);
#pragma unroll
      for (int ct = 0; ct < 4; ct++) {
        fragA of = *(const fragA*)(ob + (ct * 16 + lr) * 64 + kk * 32 + qu * 8);
        ea[ct] = mfma16(of, hbf, ea[ct]);
      }
    }
    if (lr < 2) {
#pragma unroll
      for (int ct = 0; ct < 4; ct++) {
        u16x4 pk;
        pk[0] = f2bf(ea[ct][0]); pk[1] = f2bf(ea[ct][1]);
        pk[2] = f2bf(ea[ct][2]); pk[3] = f2bf(ea[ct][3]);
        *(u16x4*)(Hb + fl * 136 + lr * 64 + ct * 16 + qu * 4) = pk;
      }
    }
  }
  __syncthreads();

  // ---- epilogue: out = d[n,f]*h0 + eins + bias
#pragma unroll
  for (int j = 0; j < 2; j++) {
    int f = f0 + j * 16 + lr;
    float bs = bias[f];
#pragma unroll
    for (int i2 = 0; i2 < 2; i2++) {
      int n0 = hm0 + i2 * 16 + qu * 4;
      u16x4 ev = *(const u16x4*)(Hb + (j * 16 + lr) * 136 + hb_b * 64 + n0);
#pragma unroll
      for (int r = 0; r < 4; r++) {
        int rowloc = arow0 + i2 * 16 + qu * 4 + r;
        out[(R0 + rowloc) * 256 + f] =
            dscale[(n0 + r) * 256 + f] * acc[i2][j][r] + bf2f(ev[r]) + bs;
      }
    }
  }
}

// ---------------------------------------------------------------- launch
extern "C" void kernel_launch(void* const* d_in, const int* in_sizes, int n_in,
                              void* d_out, int out_size, void* d_ws, size_t ws_size,
                              hipStream_t stream) {
  const float* x    = (const float*)d_in[0];
  const float* W    = (const float*)d_in[1];
  const float* e    = (const float*)d_in[2];
  const float* bias = (const float*)d_in[3];
  const unsigned char* mask = (const unsigned char*)d_in[4];
  float* out = (float*)d_out;
  char* ws = (char*)d_ws;
  if (ws_size < (size_t)WS_NEED) return;

  k_pre<<<6176, 256, 0, stream>>>(x, e, W, mask, ws);
  k_main<<<8192, 256, 0, stream>>>(bias, ws, out);
}

// Round 5
// 300.628 us; speedup vs baseline: 1.0300x; 1.0300x over previous
//
#include <hip/hip_runtime.h>
#include <hip/hip_bf16.h>

// B=2048, N=64, C=256, F=256
// out[b,n,f] = d[f,n]*h0[b,n,f] + sum_m off[f,n,m]*h1[b,m,f] + bias[f]
// v5: v4 with the XCD-aware block mapping fixed (bb-slice owned per-XCD,
// fb cycling fast within the XCD -> xb rows L2-shared by their 8 f-siblings).

typedef __attribute__((ext_vector_type(8))) short  fragA;   // 8 bf16 = 4 VGPR
typedef __attribute__((ext_vector_type(4))) float  f32x4;
typedef __attribute__((ext_vector_type(8))) unsigned short u16x8;
typedef __attribute__((ext_vector_type(4))) unsigned short u16x4;

// workspace layout (bytes)
constexpr long OFF_OFF = 0;                          // bf16 off [256][64][64] (2 MB)
constexpr long OFF_WT  = 2l * 1024 * 1024;           // bf16 Wt flat [512][256] (256 KB)
constexpr long OFF_DS  = OFF_WT + 512l * 256 * 2;    // f32 dscale [64][256]   (64 KB)
constexpr long OFF_XB  = OFF_DS + 64l * 256 * 4;     // bf16 xb [131072][256]  (67 MB)
constexpr long WS_NEED = OFF_XB + 131072l * 256 * 2;

static __device__ inline unsigned short f2bf(float f) {
  __hip_bfloat16 h = __float2bfloat16(f);
  return __builtin_bit_cast(unsigned short, h);
}
static __device__ inline float bf2f(unsigned short u) {
  unsigned int x = ((unsigned int)u) << 16;
  return __builtin_bit_cast(float, x);
}
static __device__ __forceinline__ void gl16(const void* g, void* l) {
  __builtin_amdgcn_global_load_lds(
      (const __attribute__((address_space(1))) unsigned int*)g,
      (__attribute__((address_space(3))) unsigned int*)l, 16, 0, 0);
}
static __device__ __forceinline__ f32x4 mfma16(fragA a, fragA b, f32x4 c) {
  return __builtin_amdgcn_mfma_f32_16x16x32_bf16(a, b, c, 0, 0, 0);
}

// ---------------------------------------------------------------- k_pre
// blocks 0..4095: softmax prep; 4096..6143: x->bf16; 6144..6175: W->Wt
__global__ __launch_bounds__(256) void k_pre(const float* __restrict__ x,
                                             const float* __restrict__ e,
                                             const float* __restrict__ W,
                                             const unsigned char* __restrict__ mask,
                                             char* __restrict__ ws_b) {
  const int bid = blockIdx.x;
  const int tid = threadIdx.x;
  if (bid < 4096) {
    unsigned short* off = (unsigned short*)(ws_b + OFF_OFF);
    float* dscale = (float*)(ws_b + OFF_DS);
    const int lane = tid & 63;
    const int row  = bid * 4 + (tid >> 6);   // f*64 + n
    const int n = row & 63;
    bool is_u8 = __all(mask[lane * 65] != 0);  // diag guaranteed true
    bool mv;
    if (is_u8) mv = mask[n * 64 + lane] != 0;
    else       mv = ((const int*)mask)[n * 64 + lane] != 0;
    float v = mv ? e[(long)row * 64 + lane] : -1e30f;
    float mx = v;
#pragma unroll
    for (int s = 32; s; s >>= 1) mx = fmaxf(mx, __shfl_xor(mx, s));
    float ex = mv ? __expf(v - mx) : 0.f;
    float sm = ex;
#pragma unroll
    for (int s = 32; s; s >>= 1) sm += __shfl_xor(sm, s);
    float adj = ex / sm;
    const int f = row >> 6;
    if (lane == n) dscale[n * 256 + f] = adj;
    off[(long)row * 64 + lane] = f2bf(lane == n ? 0.f : adj);
  } else if (bid < 6144) {
    unsigned short* xb = (unsigned short*)(ws_b + OFF_XB);
    long i = ((long)(bid - 4096) * 256 + tid) * 8;
    const long stride = 2048l * 256 * 8;
    const long total = 131072l * 256;
    for (; i < total; i += stride) {
      float4 a = *(const float4*)(x + i);
      float4 b = *(const float4*)(x + i + 4);
      u16x8 p;
      p[0] = f2bf(a.x); p[1] = f2bf(a.y); p[2] = f2bf(a.z); p[3] = f2bf(a.w);
      p[4] = f2bf(b.x); p[5] = f2bf(b.y); p[6] = f2bf(b.z); p[7] = f2bf(b.w);
      *(u16x8*)(xb + i) = p;
    }
  } else {
    unsigned short* Wt = (unsigned short*)(ws_b + OFF_WT);
    __shared__ float t[64][65];
    const int b2 = bid - 6144;          // 32 blocks: w(2) x f0(4) x c0(4)
    const int w = b2 >> 4, f0 = ((b2 >> 2) & 3) * 64, c0 = (b2 & 3) * 64;
    const int tr = tid >> 2, tc = (tid & 3) * 16;
    const float* src = W + ((long)(w * 256 + c0 + tr)) * 256 + f0 + tc;
#pragma unroll
    for (int i = 0; i < 16; i += 4) {
      float4 v = *(const float4*)(src + i);
      t[tr][tc + i] = v.x; t[tr][tc + i + 1] = v.y;
      t[tr][tc + i + 2] = v.z; t[tr][tc + i + 3] = v.w;
    }
    __syncthreads();
    u16x8 p0, p1;
#pragma unroll
    for (int i = 0; i < 8; i++)  p0[i] = f2bf(t[tc + i][tr]);
#pragma unroll
    for (int i = 0; i < 8; i++)  p1[i] = f2bf(t[tc + 8 + i][tr]);
    unsigned short* dst = Wt + ((long)(w * 256 + f0 + tr)) * 256 + c0 + tc;
    *(u16x8*)dst = p0;
    *(u16x8*)(dst + 8) = p1;
  }
}

// ---------------------------------------------------------------- k_main
// grid 8192, block 256. XCD-aware: xcd = wg&7 owns bb in [xcd*128,(xcd+1)*128),
// fb cycles fast among consecutive blocks on the same XCD (xb rows L2-shared).
// Tile: 128 rows (2 batches) x 64 cols (32 f x {h0,h1}), K=256 in 4 steps.
// Arena: [0,16K) A-tile (later Hb), [16K,48K) B-tile. XOR-swizzled LDS.
__global__ __launch_bounds__(256) void k_main(const float* __restrict__ bias,
                                              const char* __restrict__ ws_b,
                                              float* __restrict__ out) {
  const unsigned short* offp = (const unsigned short*)(ws_b + OFF_OFF);
  const float* dscale        = (const float*)(ws_b + OFF_DS);
  const char* xb_b = ws_b + OFF_XB;
  const char* wt_b = ws_b + OFF_WT;

  __shared__ __align__(16) char arena[49152];
  unsigned short* Hb = (unsigned short*)arena;   // einsum phase: [f][b][m], stride 136

  const int tid = threadIdx.x;
  const int wid = tid >> 6, lane = tid & 63;
  const int lr = lane & 15, qu = lane >> 4;

  const int wg = blockIdx.x;
  const int xcd = wg & 7, s = wg >> 3;           // s in 0..1023
  const int bb = xcd * 128 + (s >> 3);           // 0..1023 row-groups of 128
  const int fb = s & 7;
  const int f0 = fb * 32;
  const long R0 = (long)bb * 128;

  // ---- stage B once: 64 cols x 512B, source pre-permuted for XOR swizzle
  {
    const int c  = tid >> 5;             // col within 8-group
    const int cb = (tid & 31) * 16;
    const int sw = cb ^ ((c & 7) << 4);
#pragma unroll
    for (int i = 0; i < 8; i++) {
      int col  = i * 8 + c;
      int wrow = (col < 32) ? (f0 + col) : (224 + f0 + col);  // 256+f0+(col-32)
      gl16(wt_b + (long)wrow * 512 + sw, arena + 16384 + i * 4096 + tid * 16);
    }
  }
  // ---- stage A (ks=0)
  const int ar = tid >> 3;                       // row within 32-group
  const int aswz = ((tid & 7) ^ (ar & 7)) << 4;  // permuted 16B slot in 128B chunk
#pragma unroll
  for (int i = 0; i < 4; i++)
    gl16(xb_b + (R0 + i * 32 + ar) * 512 + aswz, arena + i * 4096 + tid * 16);

  f32x4 acc[2][4] = {};
  const int arow0 = wid * 32;

  for (int ks = 0; ks < 4; ks++) {
    __syncthreads();                 // drains vmcnt(0): staged tiles visible
    fragA af[2][2], bf_[2][4];
#pragma unroll
    for (int kk = 0; kk < 2; kk++) {
#pragma unroll
      for (int i2 = 0; i2 < 2; i2++) {
        int r = arow0 + i2 * 16 + lr;
        af[kk][i2] = *(const fragA*)(arena + r * 128 +
                        ((kk * 64 + qu * 16) ^ ((lr & 7) << 4)));
      }
#pragma unroll
      for (int j = 0; j < 4; j++) {
        int cc = j * 16 + lr;
        bf_[kk][j] = *(const fragA*)(arena + 16384 + cc * 512 +
                        ((ks * 128 + kk * 64 + qu * 16) ^ ((lr & 7) << 4)));
      }
    }
#pragma unroll
    for (int kk = 0; kk < 2; kk++)
#pragma unroll
      for (int i2 = 0; i2 < 2; i2++)
#pragma unroll
        for (int j = 0; j < 4; j++)
          acc[i2][j] = mfma16(af[kk][i2], bf_[kk][j], acc[i2][j]);
    __syncthreads();                 // all waves done reading A-tile
    if (ks < 3) {
#pragma unroll
      for (int i = 0; i < 4; i++)
        gl16(xb_b + (R0 + i * 32 + ar) * 512 + (ks + 1) * 128 + aswz,
             arena + i * 4096 + tid * 16);
    }
  }

  // ---- h1 (cols 32..63) -> Hb[f][b][m] (A region is dead after last barrier)
  const int hb_b = wid >> 1;             // batch index of wave's rows
  const int hm0 = (wid & 1) * 32;
#pragma unroll
  for (int j = 2; j < 4; j++) {
#pragma unroll
    for (int i2 = 0; i2 < 2; i2++) {
      int f = (j - 2) * 16 + lr;
      int m = hm0 + i2 * 16 + qu * 4;
      u16x4 pk;
      pk[0] = f2bf(acc[i2][j][0]); pk[1] = f2bf(acc[i2][j][1]);
      pk[2] = f2bf(acc[i2][j][2]); pk[3] = f2bf(acc[i2][j][3]);
      *(u16x4*)(Hb + f * 136 + hb_b * 64 + m) = pk;
    }
  }
  __syncthreads();

  // ---- einsum: wave owns f = wid*8+q. C[n,b] = sum_m off[f,n,m]*h1[b,m].
  // A = off rows n (global, L2-resident slice); B = h1 cols b (2 of 16 valid).
  // Result bf16 written in place over Hb[f] (wave-private f).
#pragma unroll 2
  for (int q = 0; q < 8; q++) {
    int fl = wid * 8 + q;
    const unsigned short* ob = offp + (long)(f0 + fl) * 4096;
    f32x4 ea[4] = {};
#pragma unroll
    for (int kk = 0; kk < 2; kk++) {
      fragA hbf = *(const fragA*)(Hb + fl * 136 + (lr & 1) * 64 + kk * 32 + qu * 8);
#pragma unroll
      for (int ct = 0; ct < 4; ct++) {
        fragA of = *(const fragA*)(ob + (ct * 16 + lr) * 64 + kk * 32 + qu * 8);
        ea[ct] = mfma16(of, hbf, ea[ct]);
      }
    }
    if (lr < 2) {
#pragma unroll
      for (int ct = 0; ct < 4; ct++) {
        u16x4 pk;
        pk[0] = f2bf(ea[ct][0]); pk[1] = f2bf(ea[ct][1]);
        pk[2] = f2bf(ea[ct][2]); pk[3] = f2bf(ea[ct][3]);
        *(u16x4*)(Hb + fl * 136 + lr * 64 + ct * 16 + qu * 4) = pk;
      }
    }
  }
  __syncthreads();

  // ---- epilogue: out = d[n,f]*h0 + eins + bias
#pragma unroll
  for (int j = 0; j < 2; j++) {
    int f = f0 + j * 16 + lr;
    float bs = bias[f];
#pragma unroll
    for (int i2 = 0; i2 < 2; i2++) {
      int n0 = hm0 + i2 * 16 + qu * 4;
      u16x4 ev = *(const u16x4*)(Hb + (j * 16 + lr) * 136 + hb_b * 64 + n0);
#pragma unroll
      for (int r = 0; r < 4; r++) {
        int rowloc = arow0 + i2 * 16 + qu * 4 + r;
        out[(R0 + rowloc) * 256 + f] =
            dscale[(n0 + r) * 256 + f] * acc[i2][j][r] + bf2f(ev[r]) + bs;
      }
    }
  }
}

// ---------------------------------------------------------------- launch
extern "C" void kernel_launch(void* const* d_in, const int* in_sizes, int n_in,
                              void* d_out, int out_size, void* d_ws, size_t ws_size,
                              hipStream_t stream) {
  const float* x    = (const float*)d_in[0];
  const float* W    = (const float*)d_in[1];
  const float* e    = (const float*)d_in[2];
  const float* bias = (const float*)d_in[3];
  const unsigned char* mask = (const unsigned char*)d_in[4];
  float* out = (float*)d_out;
  char* ws = (char*)d_ws;
  if (ws_size < (size_t)WS_NEED) return;

  k_pre<<<6176, 256, 0, stream>>>(x, e, W, mask, ws);
  k_main<<<8192, 256, 0, stream>>>(bias, ws, out);
}

// Round 6
// 239.554 us; speedup vs baseline: 1.2926x; 1.2549x over previous
//
#include <hip/hip_runtime.h>
#include <hip/hip_bf16.h>

// B=2048, N=64, C=256, F=256
// out[b,n,f] = d[f,n]*h0[b,n,f] + sum_m off[f,n,m]*h1[b,m,f] + bias[f]
// v6 (de-fused, 3 kernels):
//  k_pre : off/dscale softmax prep, W->Wt bf16, x->xb bf16
//  k_gemm: h0,h1 = xb@Wt (dbuf gl16 staging, 1 barrier/K-step);
//          writes g0 = dscale*h0 (bf16 [row][f]) and h1t (bf16 [f][row])
//  k_eout: eins[n,b] per f via MFMA (no wasted lanes), LDS transpose,
//          out = g0 + eins + bias (single f32 write, no RMW)

typedef __attribute__((ext_vector_type(8))) short  fragA;   // 8 bf16 = 4 VGPR
typedef __attribute__((ext_vector_type(4))) float  f32x4;
typedef __attribute__((ext_vector_type(8))) unsigned short u16x8;
typedef __attribute__((ext_vector_type(4))) unsigned short u16x4;

// workspace layout (bytes)
constexpr long OFF_OFF = 0;                          // bf16 off [256][64][64] (2 MB)
constexpr long OFF_WT  = 2l * 1024 * 1024;           // bf16 Wt flat [512][256] (256 KB)
constexpr long OFF_DS  = OFF_WT + 512l * 256 * 2;    // f32 dscale [64][256]   (64 KB)
constexpr long OFF_XB  = OFF_DS + 64l * 256 * 4;     // bf16 xb  [131072][256] (67 MB)
constexpr long OFF_G0  = OFF_XB + 131072l * 256 * 2; // bf16 g0  [131072][256] (67 MB)
constexpr long OFF_H1T = OFF_G0 + 131072l * 256 * 2; // bf16 h1t [256][131072] (67 MB)
constexpr long WS_NEED = OFF_H1T + 131072l * 256 * 2;

static __device__ inline unsigned short f2bf(float f) {
  __hip_bfloat16 h = __float2bfloat16(f);
  return __builtin_bit_cast(unsigned short, h);
}
static __device__ inline float bf2f(unsigned short u) {
  unsigned int x = ((unsigned int)u) << 16;
  return __builtin_bit_cast(float, x);
}
static __device__ __forceinline__ void gl16(const void* g, void* l) {
  __builtin_amdgcn_global_load_lds(
      (const __attribute__((address_space(1))) unsigned int*)g,
      (__attribute__((address_space(3))) unsigned int*)l, 16, 0, 0);
}
static __device__ __forceinline__ f32x4 mfma16(fragA a, fragA b, f32x4 c) {
  return __builtin_amdgcn_mfma_f32_16x16x32_bf16(a, b, c, 0, 0, 0);
}

// ---------------------------------------------------------------- k_pre
// blocks 0..4095: softmax prep; 4096..6143: x->bf16; 6144..6175: W->Wt
__global__ __launch_bounds__(256) void k_pre(const float* __restrict__ x,
                                             const float* __restrict__ e,
                                             const float* __restrict__ W,
                                             const unsigned char* __restrict__ mask,
                                             char* __restrict__ ws_b) {
  const int bid = blockIdx.x;
  const int tid = threadIdx.x;
  if (bid < 4096) {
    unsigned short* off = (unsigned short*)(ws_b + OFF_OFF);
    float* dscale = (float*)(ws_b + OFF_DS);
    const int lane = tid & 63;
    const int row  = bid * 4 + (tid >> 6);   // f*64 + n
    const int n = row & 63;
    bool is_u8 = __all(mask[lane * 65] != 0);  // diag guaranteed true
    bool mv;
    if (is_u8) mv = mask[n * 64 + lane] != 0;
    else       mv = ((const int*)mask)[n * 64 + lane] != 0;
    float v = mv ? e[(long)row * 64 + lane] : -1e30f;
    float mx = v;
#pragma unroll
    for (int s = 32; s; s >>= 1) mx = fmaxf(mx, __shfl_xor(mx, s));
    float ex = mv ? __expf(v - mx) : 0.f;
    float sm = ex;
#pragma unroll
    for (int s = 32; s; s >>= 1) sm += __shfl_xor(sm, s);
    float adj = ex / sm;
    const int f = row >> 6;
    if (lane == n) dscale[n * 256 + f] = adj;
    off[(long)row * 64 + lane] = f2bf(lane == n ? 0.f : adj);
  } else if (bid < 6144) {
    unsigned short* xb = (unsigned short*)(ws_b + OFF_XB);
    long i = ((long)(bid - 4096) * 256 + tid) * 8;
    const long stride = 2048l * 256 * 8;
    const long total = 131072l * 256;
    for (; i < total; i += stride) {
      float4 a = *(const float4*)(x + i);
      float4 b = *(const float4*)(x + i + 4);
      u16x8 p;
      p[0] = f2bf(a.x); p[1] = f2bf(a.y); p[2] = f2bf(a.z); p[3] = f2bf(a.w);
      p[4] = f2bf(b.x); p[5] = f2bf(b.y); p[6] = f2bf(b.z); p[7] = f2bf(b.w);
      *(u16x8*)(xb + i) = p;
    }
  } else {
    unsigned short* Wt = (unsigned short*)(ws_b + OFF_WT);
    __shared__ float t[64][65];
    const int b2 = bid - 6144;          // 32 blocks: w(2) x f0(4) x c0(4)
    const int w = b2 >> 4, f0 = ((b2 >> 2) & 3) * 64, c0 = (b2 & 3) * 64;
    const int tr = tid >> 2, tc = (tid & 3) * 16;
    const float* src = W + ((long)(w * 256 + c0 + tr)) * 256 + f0 + tc;
#pragma unroll
    for (int i = 0; i < 16; i += 4) {
      float4 v = *(const float4*)(src + i);
      t[tr][tc + i] = v.x; t[tr][tc + i + 1] = v.y;
      t[tr][tc + i + 2] = v.z; t[tr][tc + i + 3] = v.w;
    }
    __syncthreads();
    u16x8 p0, p1;
#pragma unroll
    for (int i = 0; i < 8; i++)  p0[i] = f2bf(t[tc + i][tr]);
#pragma unroll
    for (int i = 0; i < 8; i++)  p1[i] = f2bf(t[tc + 8 + i][tr]);
    unsigned short* dst = Wt + ((long)(w * 256 + f0 + tr)) * 256 + c0 + tc;
    *(u16x8*)dst = p0;
    *(u16x8*)(dst + 8) = p1;
  }
}

// ---------------------------------------------------------------- k_gemm
// grid 8192, block 256. xcd = wg&7 owns row-groups; cg (col-group) cycles fast.
// Tile 128 rows x 64 cols (32 f x {h0,h1}), K=256 in 4 steps, A double-buffered.
// Arena: [0,32K) B; [32K,48K) Abuf0; [48K,64K) Abuf1. XOR-swizzled LDS.
__global__ __launch_bounds__(256) void k_gemm(char* __restrict__ ws_b) {
  const float* dscale = (const float*)(ws_b + OFF_DS);
  const char* xb_b = ws_b + OFF_XB;
  const char* wt_b = ws_b + OFF_WT;
  unsigned short* g0g = (unsigned short*)(ws_b + OFF_G0);
  unsigned short* h1t = (unsigned short*)(ws_b + OFF_H1T);

  __shared__ __align__(16) char arena[65536];

  const int tid = threadIdx.x;
  const int wid = tid >> 6, lane = tid & 63;
  const int lr = lane & 15, qu = lane >> 4;

  const int wg = blockIdx.x;
  const int xcd = wg & 7, s = wg >> 3;           // s 0..1023
  const int rg = xcd * 128 + (s >> 3);           // 0..1023 row-groups of 128
  const int cg = s & 7;                          // col-group cycles fast (L2 share)
  const int f0 = cg * 32;
  const long R0 = (long)rg * 128;

  // ---- stage B once: 64 cols x 512B, source pre-permuted for XOR swizzle
  {
    const int c  = tid >> 5;
    const int cb = (tid & 31) * 16;
    const int sw = cb ^ ((c & 7) << 4);
#pragma unroll
    for (int i = 0; i < 8; i++) {
      int col  = i * 8 + c;
      int wrow = (col < 32) ? (f0 + col) : (224 + f0 + col);  // 256+f0+(col-32)
      gl16(wt_b + (long)wrow * 512 + sw, arena + i * 4096 + tid * 16);
    }
  }
  // ---- stage A ks=0 into buf0
  const int ar = tid >> 3;                       // row within 32-group
  const int aswz = ((tid & 7) ^ (ar & 7)) << 4;
#pragma unroll
  for (int i = 0; i < 4; i++)
    gl16(xb_b + (R0 + i * 32 + ar) * 512 + aswz, arena + 32768 + i * 4096 + tid * 16);

  f32x4 acc[2][4] = {};
  const int arow0 = wid * 32;

  for (int ks = 0; ks < 4; ks++) {
    __syncthreads();      // drains prev stage (vmcnt0) + protects other buf
    if (ks < 3) {         // issue next A-tile BEFORE compute (overlaps it)
      const char* gsrc = xb_b + (ks + 1) * 128;
      char* ldst = arena + 32768 + ((ks + 1) & 1) * 16384;
#pragma unroll
      for (int i = 0; i < 4; i++)
        gl16(gsrc + (R0 + i * 32 + ar) * 512 + aswz, ldst + i * 4096 + tid * 16);
    }
    const char* ab = arena + 32768 + (ks & 1) * 16384;
    fragA af[2][2], bfr[2][4];
#pragma unroll
    for (int kk = 0; kk < 2; kk++) {
#pragma unroll
      for (int i2 = 0; i2 < 2; i2++) {
        int r = arow0 + i2 * 16 + lr;
        af[kk][i2] = *(const fragA*)(ab + r * 128 +
                        ((kk * 64 + qu * 16) ^ ((lr & 7) << 4)));
      }
#pragma unroll
      for (int j = 0; j < 4; j++) {
        int cc = j * 16 + lr;
        bfr[kk][j] = *(const fragA*)(arena + cc * 512 +
                        ((ks * 128 + kk * 64 + qu * 16) ^ ((lr & 7) << 4)));
      }
    }
#pragma unroll
    for (int kk = 0; kk < 2; kk++)
#pragma unroll
      for (int i2 = 0; i2 < 2; i2++)
#pragma unroll
        for (int j = 0; j < 4; j++)
          acc[i2][j] = mfma16(af[kk][i2], bfr[kk][j], acc[i2][j]);
  }
  __syncthreads();   // A-bufs free for epilogue staging

  // ---- epilogue staging: Gs [128][40] (g0), Ts [32][136] (h1 transpose)
  unsigned short* Gs = (unsigned short*)(arena + 32768);
  unsigned short* Ts = (unsigned short*)(arena + 49152);
#pragma unroll
  for (int i2 = 0; i2 < 2; i2++) {
#pragma unroll
    for (int j = 0; j < 2; j++) {      // h0 -> dscale*h0
      int f = f0 + j * 16 + lr;
#pragma unroll
      for (int r = 0; r < 4; r++) {
        int rloc = arow0 + i2 * 16 + qu * 4 + r;
        int n = rloc & 63;
        Gs[rloc * 40 + j * 16 + lr] = f2bf(dscale[n * 256 + f] * acc[i2][j][r]);
      }
    }
#pragma unroll
    for (int j = 2; j < 4; j++) {      // h1 -> Ts[fl][rloc]
      int fl = (j - 2) * 16 + lr;
      int rb = arow0 + i2 * 16 + qu * 4;
      u16x4 pk;
      pk[0] = f2bf(acc[i2][j][0]); pk[1] = f2bf(acc[i2][j][1]);
      pk[2] = f2bf(acc[i2][j][2]); pk[3] = f2bf(acc[i2][j][3]);
      *(u16x4*)(Ts + fl * 136 + rb) = pk;
    }
  }
  __syncthreads();

  // ---- coalesced global writes
  {   // g0: 2 threads/row, 32B each
    int row = tid >> 1, half = tid & 1;
    const unsigned short* sp = Gs + row * 40 + half * 16;
    unsigned short* dp = g0g + (R0 + row) * 256 + f0 + half * 16;
    *(u16x8*)dp = *(const u16x8*)sp;
    *(u16x8*)(dp + 8) = *(const u16x8*)(sp + 8);
  }
  {   // h1t: 8 threads/f, 32B each (256B per f-row contiguous)
    int f = tid >> 3, seg = tid & 7;
    const unsigned short* sp = Ts + f * 136 + seg * 16;
    unsigned short* dp = h1t + (long)(f0 + f) * 131072 + R0 + seg * 16;
    *(u16x8*)dp = *(const u16x8*)sp;
    *(u16x8*)(dp + 8) = *(const u16x8*)(sp + 8);
  }
}

// ---------------------------------------------------------------- k_eout
// grid 1024, block 256 (4 waves). Block = 16 batches x 32 f, all 64 n.
// Per f: C[n,b] = sum_m off[f,n,m] * h1[b,m]  (A=off rows n, B=h1t rows b).
// All 16x16 output lanes valid. Transpose via Es[16][64][36] (fi-XOR swizzle),
// then out = g0 + eins + bias, straight f32 write.
__global__ __launch_bounds__(256) void k_eout(const float* __restrict__ bias,
                                              const char* __restrict__ ws_b,
                                              float* __restrict__ out) {
  const unsigned short* offp = (const unsigned short*)(ws_b + OFF_OFF);
  const unsigned short* h1t  = (const unsigned short*)(ws_b + OFF_H1T);
  const unsigned short* g0g  = (const unsigned short*)(ws_b + OFF_G0);

  __shared__ __align__(16) unsigned short Es[16 * 64 * 36];   // 73728 B

  const int tid = threadIdx.x;
  const int wid = tid >> 6, lane = tid & 63;
  const int lr = lane & 15, qu = lane >> 4;

  const int wg = blockIdx.x;
  const int xcd = wg & 7, u = wg >> 3;           // u 0..127
  const int bg = xcd * 16 + (u >> 3);            // 0..127 (16-batch groups)
  const int fg = u & 7;                          // f-group cycles fast
  const long B0 = (long)bg * 16;
  const int f0 = fg * 32;

#pragma unroll 2
  for (int q = 0; q < 8; q++) {
    const int fi = wid * 8 + q;                  // 0..31
    const long fglob = f0 + fi;
    const unsigned short* hb_p = h1t + fglob * 131072 + (B0 + lr) * 64;
    const unsigned short* ob   = offp + fglob * 4096;
    fragA hb0 = *(const fragA*)(hb_p + qu * 8);
    fragA hb1 = *(const fragA*)(hb_p + 32 + qu * 8);
    f32x4 ea[4] = {};
#pragma unroll
    for (int ct = 0; ct < 4; ct++) {
      fragA o0 = *(const fragA*)(ob + (ct * 16 + lr) * 64 + qu * 8);
      fragA o1 = *(const fragA*)(ob + (ct * 16 + lr) * 64 + 32 + qu * 8);
      ea[ct] = mfma16(o0, hb0, ea[ct]);
      ea[ct] = mfma16(o1, hb1, ea[ct]);
    }
    const int fsw = fi ^ ((lr & 7) << 2);        // fi-XOR (4-aligned groups)
#pragma unroll
    for (int ct = 0; ct < 4; ct++)
#pragma unroll
      for (int r = 0; r < 4; r++) {
        int n = ct * 16 + qu * 4 + r;
        Es[lr * 2304 + n * 36 + fsw] = f2bf(ea[ct][r]);
      }
  }
  __syncthreads();

  // ---- final: out = g0 + eins + bias, 4 rows/thread
  float4 bv[8];
#pragma unroll
  for (int k = 0; k < 8; k++) bv[k] = ((const float4*)(bias + f0))[k];
#pragma unroll
  for (int i = 0; i < 4; i++) {
    int rl = tid + 256 * i;                      // 0..1023 = b*64+n
    int b = rl >> 6, n = rl & 63;
    long gRow = (B0 + b) * 64 + n;
    const unsigned short* gp = g0g + gRow * 256 + f0;
    u16x8 g[4];
#pragma unroll
    for (int k = 0; k < 4; k++) g[k] = ((const u16x8*)gp)[k];
    u16x4 ev[8];
#pragma unroll
    for (int gg = 0; gg < 8; gg++)
      ev[gg] = *(const u16x4*)&Es[b * 2304 + n * 36 + ((gg ^ (b & 7)) << 2)];
    float4* op = (float4*)(out + gRow * 256 + f0);
#pragma unroll
    for (int k = 0; k < 8; k++) {
      float4 ov;
      ov.x = bf2f(g[k >> 1][(k & 1) * 4 + 0]) + bf2f(ev[k][0]) + bv[k].x;
      ov.y = bf2f(g[k >> 1][(k & 1) * 4 + 1]) + bf2f(ev[k][1]) + bv[k].y;
      ov.z = bf2f(g[k >> 1][(k & 1) * 4 + 2]) + bf2f(ev[k][2]) + bv[k].z;
      ov.w = bf2f(g[k >> 1][(k & 1) * 4 + 3]) + bf2f(ev[k][3]) + bv[k].w;
      op[k] = ov;
    }
  }
}

// ---------------------------------------------------------------- launch
extern "C" void kernel_launch(void* const* d_in, const int* in_sizes, int n_in,
                              void* d_out, int out_size, void* d_ws, size_t ws_size,
                              hipStream_t stream) {
  const float* x    = (const float*)d_in[0];
  const float* W    = (const float*)d_in[1];
  const float* e    = (const float*)d_in[2];
  const float* bias = (const float*)d_in[3];
  const unsigned char* mask = (const unsigned char*)d_in[4];
  float* out = (float*)d_out;
  char* ws = (char*)d_ws;
  if (ws_size < (size_t)WS_NEED) return;   // visible failure if ws too small

  k_pre<<<6176, 256, 0, stream>>>(x, e, W, mask, ws);
  k_gemm<<<8192, 256, 0, stream>>>(ws);
  k_eout<<<1024, 256, 0, stream>>>(bias, ws, out);
}

// Round 7
// 227.028 us; speedup vs baseline: 1.3640x; 1.0552x over previous
//
#include <hip/hip_runtime.h>
#include <hip/hip_bf16.h>

// B=2048, N=64, C=256, F=256
// out[b,n,f] = d[f,n]*h0[b,n,f] + sum_m off[f,n,m]*h1[b,m,f] + bias[f]
// v7: occupancy fixes. k_gemm arena 48KB (per-K-step B staging, dbuf) -> 3
// blocks/CU. k_eout block = 16b x 16f, Es 36.9KB -> 4 blocks/CU, grid 2048.

typedef __attribute__((ext_vector_type(8))) short  fragA;   // 8 bf16 = 4 VGPR
typedef __attribute__((ext_vector_type(4))) float  f32x4;
typedef __attribute__((ext_vector_type(8))) unsigned short u16x8;
typedef __attribute__((ext_vector_type(4))) unsigned short u16x4;

// workspace layout (bytes)
constexpr long OFF_OFF = 0;                          // bf16 off [256][64][64] (2 MB)
constexpr long OFF_WT  = 2l * 1024 * 1024;           // bf16 Wt flat [512][256] (256 KB)
constexpr long OFF_DS  = OFF_WT + 512l * 256 * 2;    // f32 dscale [64][256]   (64 KB)
constexpr long OFF_XB  = OFF_DS + 64l * 256 * 4;     // bf16 xb  [131072][256] (67 MB)
constexpr long OFF_G0  = OFF_XB + 131072l * 256 * 2; // bf16 g0  [131072][256] (67 MB)
constexpr long OFF_H1T = OFF_G0 + 131072l * 256 * 2; // bf16 h1t [256][131072] (67 MB)
constexpr long WS_NEED = OFF_H1T + 131072l * 256 * 2;

static __device__ inline unsigned short f2bf(float f) {
  __hip_bfloat16 h = __float2bfloat16(f);
  return __builtin_bit_cast(unsigned short, h);
}
static __device__ inline float bf2f(unsigned short u) {
  unsigned int x = ((unsigned int)u) << 16;
  return __builtin_bit_cast(float, x);
}
static __device__ __forceinline__ void gl16(const void* g, void* l) {
  __builtin_amdgcn_global_load_lds(
      (const __attribute__((address_space(1))) unsigned int*)g,
      (__attribute__((address_space(3))) unsigned int*)l, 16, 0, 0);
}
static __device__ __forceinline__ f32x4 mfma16(fragA a, fragA b, f32x4 c) {
  return __builtin_amdgcn_mfma_f32_16x16x32_bf16(a, b, c, 0, 0, 0);
}

// ---------------------------------------------------------------- k_pre
// blocks 0..4095: softmax prep; 4096..6143: x->bf16; 6144..6175: W->Wt
__global__ __launch_bounds__(256) void k_pre(const float* __restrict__ x,
                                             const float* __restrict__ e,
                                             const float* __restrict__ W,
                                             const unsigned char* __restrict__ mask,
                                             char* __restrict__ ws_b) {
  const int bid = blockIdx.x;
  const int tid = threadIdx.x;
  if (bid < 4096) {
    unsigned short* off = (unsigned short*)(ws_b + OFF_OFF);
    float* dscale = (float*)(ws_b + OFF_DS);
    const int lane = tid & 63;
    const int row  = bid * 4 + (tid >> 6);   // f*64 + n
    const int n = row & 63;
    bool is_u8 = __all(mask[lane * 65] != 0);  // diag guaranteed true
    bool mv;
    if (is_u8) mv = mask[n * 64 + lane] != 0;
    else       mv = ((const int*)mask)[n * 64 + lane] != 0;
    float v = mv ? e[(long)row * 64 + lane] : -1e30f;
    float mx = v;
#pragma unroll
    for (int s = 32; s; s >>= 1) mx = fmaxf(mx, __shfl_xor(mx, s));
    float ex = mv ? __expf(v - mx) : 0.f;
    float sm = ex;
#pragma unroll
    for (int s = 32; s; s >>= 1) sm += __shfl_xor(sm, s);
    float adj = ex / sm;
    const int f = row >> 6;
    if (lane == n) dscale[n * 256 + f] = adj;
    off[(long)row * 64 + lane] = f2bf(lane == n ? 0.f : adj);
  } else if (bid < 6144) {
    unsigned short* xb = (unsigned short*)(ws_b + OFF_XB);
    long i = ((long)(bid - 4096) * 256 + tid) * 8;
    const long stride = 2048l * 256 * 8;
    const long total = 131072l * 256;
    for (; i < total; i += stride) {
      float4 a = *(const float4*)(x + i);
      float4 b = *(const float4*)(x + i + 4);
      u16x8 p;
      p[0] = f2bf(a.x); p[1] = f2bf(a.y); p[2] = f2bf(a.z); p[3] = f2bf(a.w);
      p[4] = f2bf(b.x); p[5] = f2bf(b.y); p[6] = f2bf(b.z); p[7] = f2bf(b.w);
      *(u16x8*)(xb + i) = p;
    }
  } else {
    unsigned short* Wt = (unsigned short*)(ws_b + OFF_WT);
    __shared__ float t[64][65];
    const int b2 = bid - 6144;          // 32 blocks: w(2) x f0(4) x c0(4)
    const int w = b2 >> 4, f0 = ((b2 >> 2) & 3) * 64, c0 = (b2 & 3) * 64;
    const int tr = tid >> 2, tc = (tid & 3) * 16;
    const float* src = W + ((long)(w * 256 + c0 + tr)) * 256 + f0 + tc;
#pragma unroll
    for (int i = 0; i < 16; i += 4) {
      float4 v = *(const float4*)(src + i);
      t[tr][tc + i] = v.x; t[tr][tc + i + 1] = v.y;
      t[tr][tc + i + 2] = v.z; t[tr][tc + i + 3] = v.w;
    }
    __syncthreads();
    u16x8 p0, p1;
#pragma unroll
    for (int i = 0; i < 8; i++)  p0[i] = f2bf(t[tc + i][tr]);
#pragma unroll
    for (int i = 0; i < 8; i++)  p1[i] = f2bf(t[tc + 8 + i][tr]);
    unsigned short* dst = Wt + ((long)(w * 256 + f0 + tr)) * 256 + c0 + tc;
    *(u16x8*)dst = p0;
    *(u16x8*)(dst + 8) = p1;
  }
}

// ---------------------------------------------------------------- k_gemm
// grid 8192, block 256. xcd = wg&7 owns row-groups; cg cycles fast (L2 share).
// Tile 128 rows x 64 cols (32 f x {h0,h1}), K=256 in 4 steps.
// Arena 48KB: A0@0, A1@16K (16K each); B0@32K, B1@40K (8K each, per-K-step).
__global__ __launch_bounds__(256) void k_gemm(char* __restrict__ ws_b) {
  const float* dscale = (const float*)(ws_b + OFF_DS);
  const char* xb_b = ws_b + OFF_XB;
  const char* wt_b = ws_b + OFF_WT;
  unsigned short* g0g = (unsigned short*)(ws_b + OFF_G0);
  unsigned short* h1t = (unsigned short*)(ws_b + OFF_H1T);

  __shared__ __align__(16) char arena[49152];

  const int tid = threadIdx.x;
  const int wid = tid >> 6, lane = tid & 63;
  const int lr = lane & 15, qu = lane >> 4;

  const int wg = blockIdx.x;
  const int xcd = wg & 7, s = wg >> 3;           // s 0..1023
  const int rg = xcd * 128 + (s >> 3);           // 0..1023 row-groups of 128
  const int cg = s & 7;                          // col-group cycles fast
  const int f0 = cg * 32;
  const long R0 = (long)rg * 128;

  const int ar   = tid >> 3;                     // row within 32-group
  const int swz  = (((tid & 7) ^ (ar & 7)) << 4);  // pre-permuted 16B slot

  // B-col metadata for staging (c&7 == (tid>>3)&7)
  const int bc0 = tid >> 3;                      // col for i=0 (0..31)
  const int wrow0 = f0 + bc0;                    // cols 0..31 -> W0 rows
  const int wrow1 = 224 + f0 + (bc0 + 32);       // cols 32..63 -> W1 rows

  // ---- prologue: stage A(0)->A0, B(0)->B0
#pragma unroll
  for (int i = 0; i < 4; i++)
    gl16(xb_b + (R0 + i * 32 + ar) * 512 + swz, arena + i * 4096 + tid * 16);
  gl16(wt_b + (long)wrow0 * 512 + swz, arena + 32768 + tid * 16);
  gl16(wt_b + (long)wrow1 * 512 + swz, arena + 32768 + 4096 + tid * 16);

  f32x4 acc[2][4] = {};
  const int arow0 = wid * 32;

  for (int ks = 0; ks < 4; ks++) {
    __syncthreads();      // staged tiles for ks visible (vmcnt drained)
    if (ks < 3) {         // stage ks+1 before compute (overlaps MFMA)
      const int nb = (ks + 1) & 1;
      const long ko = (ks + 1) * 128;
#pragma unroll
      for (int i = 0; i < 4; i++)
        gl16(xb_b + (R0 + i * 32 + ar) * 512 + ko + swz,
             arena + nb * 16384 + i * 4096 + tid * 16);
      gl16(wt_b + (long)wrow0 * 512 + ko + swz,
           arena + 32768 + nb * 8192 + tid * 16);
      gl16(wt_b + (long)wrow1 * 512 + ko + swz,
           arena + 32768 + nb * 8192 + 4096 + tid * 16);
    }
    const char* ab = arena + (ks & 1) * 16384;
    const char* bb = arena + 32768 + (ks & 1) * 8192;
    fragA af[2][2], bfr[2][4];
#pragma unroll
    for (int kk = 0; kk < 2; kk++) {
#pragma unroll
      for (int i2 = 0; i2 < 2; i2++) {
        int r = arow0 + i2 * 16 + lr;
        af[kk][i2] = *(const fragA*)(ab + r * 128 +
                        ((kk * 64 + qu * 16) ^ ((lr & 7) << 4)));
      }
#pragma unroll
      for (int j = 0; j < 4; j++) {
        int cc = j * 16 + lr;
        bfr[kk][j] = *(const fragA*)(bb + cc * 128 +
                        ((kk * 64 + qu * 16) ^ ((lr & 7) << 4)));
      }
    }
#pragma unroll
    for (int kk = 0; kk < 2; kk++)
#pragma unroll
      for (int i2 = 0; i2 < 2; i2++)
#pragma unroll
        for (int j = 0; j < 4; j++)
          acc[i2][j] = mfma16(af[kk][i2], bfr[kk][j], acc[i2][j]);
  }
  __syncthreads();   // arena free for epilogue staging

  // ---- epilogue staging: Gs [128][40] @A0, Ts [32][136] @A1
  unsigned short* Gs = (unsigned short*)(arena);
  unsigned short* Ts = (unsigned short*)(arena + 16384);
#pragma unroll
  for (int i2 = 0; i2 < 2; i2++) {
#pragma unroll
    for (int j = 0; j < 2; j++) {      // h0 -> dscale*h0
      int f = f0 + j * 16 + lr;
#pragma unroll
      for (int r = 0; r < 4; r++) {
        int rloc = arow0 + i2 * 16 + qu * 4 + r;
        int n = rloc & 63;
        Gs[rloc * 40 + j * 16 + lr] = f2bf(dscale[n * 256 + f] * acc[i2][j][r]);
      }
    }
#pragma unroll
    for (int j = 2; j < 4; j++) {      // h1 -> Ts[fl][rloc]
      int fl = (j - 2) * 16 + lr;
      int rb = arow0 + i2 * 16 + qu * 4;
      u16x4 pk;
      pk[0] = f2bf(acc[i2][j][0]); pk[1] = f2bf(acc[i2][j][1]);
      pk[2] = f2bf(acc[i2][j][2]); pk[3] = f2bf(acc[i2][j][3]);
      *(u16x4*)(Ts + fl * 136 + rb) = pk;
    }
  }
  __syncthreads();

  // ---- coalesced global writes
  {   // g0: 2 threads/row, 32B each
    int row = tid >> 1, half = tid & 1;
    const unsigned short* sp = Gs + row * 40 + half * 16;
    unsigned short* dp = g0g + (R0 + row) * 256 + f0 + half * 16;
    *(u16x8*)dp = *(const u16x8*)sp;
    *(u16x8*)(dp + 8) = *(const u16x8*)(sp + 8);
  }
  {   // h1t: 8 threads/f, 32B each
    int f = tid >> 3, seg = tid & 7;
    const unsigned short* sp = Ts + f * 136 + seg * 16;
    unsigned short* dp = h1t + (long)(f0 + f) * 131072 + R0 + seg * 16;
    *(u16x8*)dp = *(const u16x8*)sp;
    *(u16x8*)(dp + 8) = *(const u16x8*)(sp + 8);
  }
}

// ---------------------------------------------------------------- k_eout
// grid 2048, block 256 (4 waves). Block = 16 batches x 16 f, all 64 n.
// Per f: C[n,b] = sum_m off[f,n,m] * h1[b,m]. Es[16 b][64 n][18] (36.9KB,
// odd-dword stride + 4-aligned f-XOR), then out = g0 + eins + bias.
__global__ __launch_bounds__(256) void k_eout(const float* __restrict__ bias,
                                              const char* __restrict__ ws_b,
                                              float* __restrict__ out) {
  const unsigned short* offp = (const unsigned short*)(ws_b + OFF_OFF);
  const unsigned short* h1t  = (const unsigned short*)(ws_b + OFF_H1T);
  const unsigned short* g0g  = (const unsigned short*)(ws_b + OFF_G0);

  __shared__ __align__(16) unsigned short Es[16 * 64 * 18];   // 36864 B

  const int tid = threadIdx.x;
  const int wid = tid >> 6, lane = tid & 63;
  const int lr = lane & 15, qu = lane >> 4;

  const int wg = blockIdx.x;
  const int xcd = wg & 7, u = wg >> 3;           // u 0..255
  const int bg = xcd * 16 + (u >> 4);            // 0..127 (16-batch groups)
  const int fg = u & 15;                         // f-group cycles fast
  const long B0 = (long)bg * 16;
  const int f0 = fg * 16;

#pragma unroll
  for (int q = 0; q < 4; q++) {
    const int fi = wid * 4 + q;                  // 0..15
    const long fglob = f0 + fi;
    const unsigned short* hb_p = h1t + fglob * 131072 + (B0 + lr) * 64;
    const unsigned short* ob   = offp + fglob * 4096;
    fragA hb0 = *(const fragA*)(hb_p + qu * 8);
    fragA hb1 = *(const fragA*)(hb_p + 32 + qu * 8);
    f32x4 ea[4] = {};
#pragma unroll
    for (int ct = 0; ct < 4; ct++) {
      fragA o0 = *(const fragA*)(ob + (ct * 16 + lr) * 64 + qu * 8);
      fragA o1 = *(const fragA*)(ob + (ct * 16 + lr) * 64 + 32 + qu * 8);
      ea[ct] = mfma16(o0, hb0, ea[ct]);
      ea[ct] = mfma16(o1, hb1, ea[ct]);
    }
    const int fsw = fi ^ ((lr & 3) << 2);        // 4-aligned XOR
#pragma unroll
    for (int ct = 0; ct < 4; ct++)
#pragma unroll
      for (int r = 0; r < 4; r++) {
        int n = ct * 16 + qu * 4 + r;
        Es[lr * 1152 + n * 18 + fsw] = f2bf(ea[ct][r]);
      }
  }
  __syncthreads();

  // ---- final: out = g0 + eins + bias, 4 rows/thread, 16 f each
  float4 bv[4];
#pragma unroll
  for (int k = 0; k < 4; k++) bv[k] = ((const float4*)(bias + f0))[k];
#pragma unroll
  for (int i = 0; i < 4; i++) {
    int rl = tid + 256 * i;                      // 0..1023 = b*64+n
    int b = rl >> 6, n = rl & 63;
    long gRow = (B0 + b) * 64 + n;
    const unsigned short* gp = g0g + gRow * 256 + f0;
    u16x8 gv0 = ((const u16x8*)gp)[0];
    u16x8 gv1 = ((const u16x8*)gp)[1];
    u16x4 ev[4];
#pragma unroll
    for (int gg = 0; gg < 4; gg++)
      ev[gg] = *(const u16x4*)&Es[b * 1152 + n * 18 + ((gg << 2) ^ ((b & 3) << 2))];
    float4* op = (float4*)(out + gRow * 256 + f0);
#pragma unroll
    for (int k = 0; k < 4; k++) {
      float4 ov;
      float g0e = bf2f(k < 2 ? gv0[(k & 1) * 4 + 0] : gv1[(k & 1) * 4 + 0]);
      float g1e = bf2f(k < 2 ? gv0[(k & 1) * 4 + 1] : gv1[(k & 1) * 4 + 1]);
      float g2e = bf2f(k < 2 ? gv0[(k & 1) * 4 + 2] : gv1[(k & 1) * 4 + 2]);
      float g3e = bf2f(k < 2 ? gv0[(k & 1) * 4 + 3] : gv1[(k & 1) * 4 + 3]);
      ov.x = g0e + bf2f(ev[k][0]) + bv[k].x;
      ov.y = g1e + bf2f(ev[k][1]) + bv[k].y;
      ov.z = g2e + bf2f(ev[k][2]) + bv[k].z;
      ov.w = g3e + bf2f(ev[k][3]) + bv[k].w;
      op[k] = ov;
    }
  }
}

// ---------------------------------------------------------------- launch
extern "C" void kernel_launch(void* const* d_in, const int* in_sizes, int n_in,
                              void* d_out, int out_size, void* d_ws, size_t ws_size,
                              hipStream_t stream) {
  const float* x    = (const float*)d_in[0];
  const float* W    = (const float*)d_in[1];
  const float* e    = (const float*)d_in[2];
  const float* bias = (const float*)d_in[3];
  const unsigned char* mask = (const unsigned char*)d_in[4];
  float* out = (float*)d_out;
  char* ws = (char*)d_ws;
  if (ws_size < (size_t)WS_NEED) return;

  k_pre<<<6176, 256, 0, stream>>>(x, e, W, mask, ws);
  k_gemm<<<8192, 256, 0, stream>>>(ws);
  k_eout<<<2048, 256, 0, stream>>>(bias, ws, out);
}

// Round 8
// 216.655 us; speedup vs baseline: 1.4293x; 1.0479x over previous
//
#include <hip/hip_runtime.h>
#include <hip/hip_bf16.h>

// B=2048, N=64, C=256, F=256
// out[b,n,f] = d[f,n]*h0[b,n,f] + sum_m off[f,n,m]*h1[b,m,f] + bias[f]
// v8: k_gemm -> m97 single-buffer 2-barrier, 24KB LDS, 5 blocks/CU.
//     k_eout -> Es[fi][b*68][n] (4-way writes, conflict-free reads),
//               h1t/g0 prefetch batching, launch_bounds(256,4).

typedef __attribute__((ext_vector_type(8))) short  fragA;   // 8 bf16 = 4 VGPR
typedef __attribute__((ext_vector_type(4))) float  f32x4;
typedef __attribute__((ext_vector_type(8))) unsigned short u16x8;
typedef __attribute__((ext_vector_type(4))) unsigned short u16x4;

// workspace layout (bytes)
constexpr long OFF_OFF = 0;                          // bf16 off [256][64][64] (2 MB)
constexpr long OFF_WT  = 2l * 1024 * 1024;           // bf16 Wt flat [512][256] (256 KB)
constexpr long OFF_DS  = OFF_WT + 512l * 256 * 2;    // f32 dscale [64][256]   (64 KB)
constexpr long OFF_XB  = OFF_DS + 64l * 256 * 4;     // bf16 xb  [131072][256] (67 MB)
constexpr long OFF_G0  = OFF_XB + 131072l * 256 * 2; // bf16 g0  [131072][256] (67 MB)
constexpr long OFF_H1T = OFF_G0 + 131072l * 256 * 2; // bf16 h1t [256][131072] (67 MB)
constexpr long WS_NEED = OFF_H1T + 131072l * 256 * 2;

static __device__ inline unsigned short f2bf(float f) {
  __hip_bfloat16 h = __float2bfloat16(f);
  return __builtin_bit_cast(unsigned short, h);
}
static __device__ inline float bf2f(unsigned short u) {
  unsigned int x = ((unsigned int)u) << 16;
  return __builtin_bit_cast(float, x);
}
static __device__ __forceinline__ void gl16(const void* g, void* l) {
  __builtin_amdgcn_global_load_lds(
      (const __attribute__((address_space(1))) unsigned int*)g,
      (__attribute__((address_space(3))) unsigned int*)l, 16, 0, 0);
}
static __device__ __forceinline__ f32x4 mfma16(fragA a, fragA b, f32x4 c) {
  return __builtin_amdgcn_mfma_f32_16x16x32_bf16(a, b, c, 0, 0, 0);
}

// ---------------------------------------------------------------- k_pre
// blocks 0..4095: softmax prep; 4096..6143: x->bf16; 6144..6175: W->Wt
__global__ __launch_bounds__(256) void k_pre(const float* __restrict__ x,
                                             const float* __restrict__ e,
                                             const float* __restrict__ W,
                                             const unsigned char* __restrict__ mask,
                                             char* __restrict__ ws_b) {
  const int bid = blockIdx.x;
  const int tid = threadIdx.x;
  if (bid < 4096) {
    unsigned short* off = (unsigned short*)(ws_b + OFF_OFF);
    float* dscale = (float*)(ws_b + OFF_DS);
    const int lane = tid & 63;
    const int row  = bid * 4 + (tid >> 6);   // f*64 + n
    const int n = row & 63;
    bool is_u8 = __all(mask[lane * 65] != 0);  // diag guaranteed true
    bool mv;
    if (is_u8) mv = mask[n * 64 + lane] != 0;
    else       mv = ((const int*)mask)[n * 64 + lane] != 0;
    float v = mv ? e[(long)row * 64 + lane] : -1e30f;
    float mx = v;
#pragma unroll
    for (int s = 32; s; s >>= 1) mx = fmaxf(mx, __shfl_xor(mx, s));
    float ex = mv ? __expf(v - mx) : 0.f;
    float sm = ex;
#pragma unroll
    for (int s = 32; s; s >>= 1) sm += __shfl_xor(sm, s);
    float adj = ex / sm;
    const int f = row >> 6;
    if (lane == n) dscale[n * 256 + f] = adj;
    off[(long)row * 64 + lane] = f2bf(lane == n ? 0.f : adj);
  } else if (bid < 6144) {
    unsigned short* xb = (unsigned short*)(ws_b + OFF_XB);
    long i = ((long)(bid - 4096) * 256 + tid) * 8;
    const long stride = 2048l * 256 * 8;
    const long total = 131072l * 256;
    for (; i < total; i += stride) {
      float4 a = *(const float4*)(x + i);
      float4 b = *(const float4*)(x + i + 4);
      u16x8 p;
      p[0] = f2bf(a.x); p[1] = f2bf(a.y); p[2] = f2bf(a.z); p[3] = f2bf(a.w);
      p[4] = f2bf(b.x); p[5] = f2bf(b.y); p[6] = f2bf(b.z); p[7] = f2bf(b.w);
      *(u16x8*)(xb + i) = p;
    }
  } else {
    unsigned short* Wt = (unsigned short*)(ws_b + OFF_WT);
    __shared__ float t[64][65];
    const int b2 = bid - 6144;          // 32 blocks: w(2) x f0(4) x c0(4)
    const int w = b2 >> 4, f0 = ((b2 >> 2) & 3) * 64, c0 = (b2 & 3) * 64;
    const int tr = tid >> 2, tc = (tid & 3) * 16;
    const float* src = W + ((long)(w * 256 + c0 + tr)) * 256 + f0 + tc;
#pragma unroll
    for (int i = 0; i < 16; i += 4) {
      float4 v = *(const float4*)(src + i);
      t[tr][tc + i] = v.x; t[tr][tc + i + 1] = v.y;
      t[tr][tc + i + 2] = v.z; t[tr][tc + i + 3] = v.w;
    }
    __syncthreads();
    u16x8 p0, p1;
#pragma unroll
    for (int i = 0; i < 8; i++)  p0[i] = f2bf(t[tc + i][tr]);
#pragma unroll
    for (int i = 0; i < 8; i++)  p1[i] = f2bf(t[tc + 8 + i][tr]);
    unsigned short* dst = Wt + ((long)(w * 256 + f0 + tr)) * 256 + c0 + tc;
    *(u16x8*)dst = p0;
    *(u16x8*)(dst + 8) = p1;
  }
}

// ---------------------------------------------------------------- k_gemm
// grid 8192, block 256 (4 waves), launch_bounds(256,5) -> 5 blocks/CU.
// Tile 128 rows x 64 cols (32 f x {h0,h1}), K=256 in 4 steps.
// SINGLE-buffered arena 24KB: A @0 [128 rows][128 B], B @16384 [64 cols][128 B].
// m97 2-barrier loop: barrier(tiles ready); compute; barrier; stage next.
__global__ __launch_bounds__(256, 5) void k_gemm(char* __restrict__ ws_b) {
  const float* dscale = (const float*)(ws_b + OFF_DS);
  const char* xb_b = ws_b + OFF_XB;
  const char* wt_b = ws_b + OFF_WT;
  unsigned short* g0g = (unsigned short*)(ws_b + OFF_G0);
  unsigned short* h1t = (unsigned short*)(ws_b + OFF_H1T);

  __shared__ __align__(16) char arena[24576];

  const int tid = threadIdx.x;
  const int wid = tid >> 6, lane = tid & 63;
  const int lr = lane & 15, qu = lane >> 4;

  const int wg = blockIdx.x;
  const int xcd = wg & 7, s = wg >> 3;           // s 0..1023
  const int rg = xcd * 128 + (s >> 3);           // 0..1023 row-groups of 128
  const int cg = s & 7;                          // col-group cycles fast (L2)
  const int f0 = cg * 32;
  const long R0 = (long)rg * 128;

  const int ar   = tid >> 3;                     // 0..31
  const int aswz = (((tid & 7) ^ (ar & 7)) << 4);
  const int wrow0 = f0 + ar;                     // B cols 0..31 (W0)
  const int wrow1 = 256 + f0 + ar;               // B cols 32..63 (W1)

  // ---- stage K-step ks (A 4 gl16 + B 2 gl16 per thread)
  auto STAGE = [&](int ks) {
    const long ko = (long)ks * 128;
#pragma unroll
    for (int i = 0; i < 4; i++)
      gl16(xb_b + (R0 + i * 32 + ar) * 512 + ko + aswz,
           arena + i * 4096 + tid * 16);
    gl16(wt_b + (long)wrow0 * 512 + ko + aswz, arena + 16384 + tid * 16);
    gl16(wt_b + (long)wrow1 * 512 + ko + aswz, arena + 16384 + 4096 + tid * 16);
  };

  STAGE(0);
  f32x4 acc[2][4] = {};
  const int arow0 = wid * 32;

  for (int ks = 0; ks < 4; ks++) {
    __syncthreads();      // vmcnt drained -> tiles visible
#pragma unroll
    for (int kk = 0; kk < 2; kk++) {   // kk-split keeps live frags low
      fragA af[2], bfr[4];
#pragma unroll
      for (int i2 = 0; i2 < 2; i2++) {
        int r = arow0 + i2 * 16 + lr;
        af[i2] = *(const fragA*)(arena + r * 128 +
                     ((kk * 64 + qu * 16) ^ ((lr & 7) << 4)));
      }
#pragma unroll
      for (int j = 0; j < 4; j++) {
        int cc = j * 16 + lr;
        bfr[j] = *(const fragA*)(arena + 16384 + cc * 128 +
                     ((kk * 64 + qu * 16) ^ ((lr & 7) << 4)));
      }
#pragma unroll
      for (int i2 = 0; i2 < 2; i2++)
#pragma unroll
        for (int j = 0; j < 4; j++)
          acc[i2][j] = mfma16(af[i2], bfr[j], acc[i2][j]);
    }
    __syncthreads();      // all waves done reading this tile
    if (ks < 3) STAGE(ks + 1);
  }

  // ---- epilogue staging: Gs [128][40] @0 (10240 B), Ts [32][136] @10240
  unsigned short* Gs = (unsigned short*)(arena);
  unsigned short* Ts = (unsigned short*)(arena + 10240);
#pragma unroll
  for (int i2 = 0; i2 < 2; i2++) {
#pragma unroll
    for (int j = 0; j < 2; j++) {      // h0 -> dscale*h0
      int f = f0 + j * 16 + lr;
#pragma unroll
      for (int r = 0; r < 4; r++) {
        int rloc = arow0 + i2 * 16 + qu * 4 + r;
        int n = rloc & 63;
        Gs[rloc * 40 + j * 16 + lr] = f2bf(dscale[n * 256 + f] * acc[i2][j][r]);
      }
    }
#pragma unroll
    for (int j = 2; j < 4; j++) {      // h1 -> Ts[fl][rloc]
      int fl = (j - 2) * 16 + lr;
      int rb = arow0 + i2 * 16 + qu * 4;
      u16x4 pk;
      pk[0] = f2bf(acc[i2][j][0]); pk[1] = f2bf(acc[i2][j][1]);
      pk[2] = f2bf(acc[i2][j][2]); pk[3] = f2bf(acc[i2][j][3]);
      *(u16x4*)(Ts + fl * 136 + rb) = pk;
    }
  }
  __syncthreads();

  // ---- coalesced global writes
  {   // g0: 2 threads/row, 32B each
    int row = tid >> 1, half = tid & 1;
    const unsigned short* sp = Gs + row * 40 + half * 16;
    unsigned short* dp = g0g + (R0 + row) * 256 + f0 + half * 16;
    *(u16x8*)dp = *(const u16x8*)sp;
    *(u16x8*)(dp + 8) = *(const u16x8*)(sp + 8);
  }
  {   // h1t: 8 threads/f, 32B each
    int f = tid >> 3, seg = tid & 7;
    const unsigned short* sp = Ts + f * 136 + seg * 16;
    unsigned short* dp = h1t + (long)(f0 + f) * 131072 + R0 + seg * 16;
    *(u16x8*)dp = *(const u16x8*)sp;
    *(u16x8*)(dp + 8) = *(const u16x8*)(sp + 8);
  }
}

// ---------------------------------------------------------------- k_eout
// grid 2048, block 256 (4 waves). Block = 16 batches x 16 f, all 64 n.
// Per f: C[n,b] = sum_m off[f,n,m] * h1[b,m]. Es[fi][b][n]: fi-stride 1088,
// b-stride 68 shorts (34 dw = 2 mod 32): u16x4 writes ~4-way, reads
// conflict-free. h1t frags and g0 prefetched in batches.
__global__ __launch_bounds__(256, 4) void k_eout(const float* __restrict__ bias,
                                                 const char* __restrict__ ws_b,
                                                 float* __restrict__ out) {
  const unsigned short* offp = (const unsigned short*)(ws_b + OFF_OFF);
  const unsigned short* h1t  = (const unsigned short*)(ws_b + OFF_H1T);
  const unsigned short* g0g  = (const unsigned short*)(ws_b + OFF_G0);

  __shared__ __align__(16) unsigned short Es[16 * 1088];   // 34816 B

  const int tid = threadIdx.x;
  const int wid = tid >> 6, lane = tid & 63;
  const int lr = lane & 15, qu = lane >> 4;

  const int wg = blockIdx.x;
  const int xcd = wg & 7, u = wg >> 3;           // u 0..255
  const int bg = xcd * 16 + (u >> 4);            // 0..127 (16-batch groups)
  const int fg = u & 15;                         // f-group cycles fast
  const long B0 = (long)bg * 16;
  const int f0 = fg * 16;

  // ---- prefetch all 8 h1t fragments (8 loads in flight)
  fragA hb0[4], hb1[4];
#pragma unroll
  for (int q = 0; q < 4; q++) {
    const unsigned short* hp =
        h1t + (long)(f0 + wid * 4 + q) * 131072 + (B0 + lr) * 64 + qu * 8;
    hb0[q] = *(const fragA*)hp;
    hb1[q] = *(const fragA*)(hp + 32);
  }

#pragma unroll
  for (int q = 0; q < 4; q++) {
    const int fi = wid * 4 + q;                  // 0..15
    const unsigned short* ob = offp + (long)(f0 + fi) * 4096;
    f32x4 ea[4] = {};
#pragma unroll
    for (int ct = 0; ct < 4; ct++) {
      fragA o0 = *(const fragA*)(ob + (ct * 16 + lr) * 64 + qu * 8);
      fragA o1 = *(const fragA*)(ob + (ct * 16 + lr) * 64 + 32 + qu * 8);
      ea[ct] = mfma16(o0, hb0[q], ea[ct]);
      ea[ct] = mfma16(o1, hb1[q], ea[ct]);
    }
    // lane holds (n = ct*16+qu*4+r, b = lr); u16x4 write along r-contig n
#pragma unroll
    for (int ct = 0; ct < 4; ct++) {
      u16x4 pk;
      pk[0] = f2bf(ea[ct][0]); pk[1] = f2bf(ea[ct][1]);
      pk[2] = f2bf(ea[ct][2]); pk[3] = f2bf(ea[ct][3]);
      *(u16x4*)&Es[fi * 1088 + lr * 68 + ct * 16 + qu * 4] = pk;
    }
  }

  // ---- prefetch g0 rows before the barrier (independent of Es)
  u16x8 gv[4][2];
#pragma unroll
  for (int i = 0; i < 4; i++) {
    int rl = tid + 256 * i;
    int b = rl >> 6, n = rl & 63;
    const unsigned short* gp = g0g + ((B0 + b) * 64 + n) * 256 + f0;
    gv[i][0] = ((const u16x8*)gp)[0];
    gv[i][1] = ((const u16x8*)gp)[1];
  }
  float4 bv[4];
#pragma unroll
  for (int k = 0; k < 4; k++) bv[k] = ((const float4*)(bias + f0))[k];

  __syncthreads();

  // ---- final: out = g0 + eins + bias
#pragma unroll
  for (int i = 0; i < 4; i++) {
    int rl = tid + 256 * i;                      // 0..1023 = b*64+n
    int b = rl >> 6, n = rl & 63;
    float es[16];
#pragma unroll
    for (int k = 0; k < 16; k++)
      es[k] = bf2f(Es[k * 1088 + b * 68 + n]);   // stride 544 dw: banks by b,n only
    float4* op = (float4*)(out + ((B0 + b) * 64 + n) * 256 + f0);
#pragma unroll
    for (int k = 0; k < 4; k++) {
      float4 ov;
      ov.x = bf2f(gv[i][k >> 1][(k & 1) * 4 + 0]) + es[k * 4 + 0] + bv[k].x;
      ov.y = bf2f(gv[i][k >> 1][(k & 1) * 4 + 1]) + es[k * 4 + 1] + bv[k].y;
      ov.z = bf2f(gv[i][k >> 1][(k & 1) * 4 + 2]) + es[k * 4 + 2] + bv[k].z;
      ov.w = bf2f(gv[i][k >> 1][(k & 1) * 4 + 3]) + es[k * 4 + 3] + bv[k].w;
      op[k] = ov;
    }
  }
}

// ---------------------------------------------------------------- launch
extern "C" void kernel_launch(void* const* d_in, const int* in_sizes, int n_in,
                              void* d_out, int out_size, void* d_ws, size_t ws_size,
                              hipStream_t stream) {
  const float* x    = (const float*)d_in[0];
  const float* W    = (const float*)d_in[1];
  const float* e    = (const float*)d_in[2];
  const float* bias = (const float*)d_in[3];
  const unsigned char* mask = (const unsigned char*)d_in[4];
  float* out = (float*)d_out;
  char* ws = (char*)d_ws;
  if (ws_size < (size_t)WS_NEED) return;

  k_pre<<<6176, 256, 0, stream>>>(x, e, W, mask, ws);
  k_gemm<<<8192, 256, 0, stream>>>(ws);
  k_eout<<<2048, 256, 0, stream>>>(bias, ws, out);
}